// Round 1
// baseline (138.933 us; speedup 1.0000x reference)
//
#include <hip/hip_runtime.h>
#include <math.h>

#define SA 20        // alphabet
#define KDIM 2
#define MDIM 2
#define BDIM 512
#define LDIM 512
#define NRATES 512

__device__ __forceinline__ float softplusf(float x) {
    // logaddexp(x, 0) = max(x,0) + log1p(exp(-|x|))
    return fmaxf(x, 0.0f) + log1pf(expf(-fabsf(x)));
}

// ---------------- Kernel 1: build normalized rate matrices Q (m,k,20,20) ----
__global__ void qmat_kernel(const float* __restrict__ Ek,
                            const float* __restrict__ eqk,
                            float* __restrict__ Qout) {
    const int g = blockIdx.x;          // g = m*KDIM + kk
    const int lane = threadIdx.x;
    if (lane >= 32) return;            // single wave, lower half only
    const bool act = lane < SA;

    // softmax over equilibrium kernel -> p
    float e = act ? eqk[g * SA + lane] : -INFINITY;
    float mx = e;
    #pragma unroll
    for (int off = 16; off; off >>= 1) mx = fmaxf(mx, __shfl_xor(mx, off, 32));
    float ex = act ? expf(e - mx) : 0.0f;
    float sm = ex;
    #pragma unroll
    for (int off = 16; off; off >>= 1) sm += __shfl_xor(sm, off, 32);
    float p_i = ex / sm;

    __shared__ float sp[SA];
    if (act) sp[lane] = p_i;
    // single wave: LDS write->read ordered by hardware + compiler waitcnt

    float q0[SA];
    float dg = 0.0f;
    const int i = lane;
    if (act) {
        #pragma unroll
        for (int j = 0; j < SA; ++j) {
            float e1 = Ek[(g * SA + i) * SA + j];
            float e2 = Ek[(g * SA + j) * SA + i];
            float r = (j == i) ? 0.0f : softplusf(0.5f * (e1 + e2));
            float q = r * sp[j];
            q0[j] = q;
            dg += q;
        }
    } else {
        #pragma unroll
        for (int j = 0; j < SA; ++j) q0[j] = 0.0f;
    }
    // mue = sum_i p_i * diag_i
    float t = act ? p_i * dg : 0.0f;
    #pragma unroll
    for (int off = 16; off; off >>= 1) t += __shfl_xor(t, off, 32);
    float inv = 1.0f / fmaxf(t, 1e-16f);
    if (act) {
        #pragma unroll
        for (int j = 0; j < SA; ++j) {
            float q = (j == i) ? -dg : q0[j];
            Qout[(g * SA + i) * SA + j] = q * inv;
        }
    }
}

// 20x20 matmul, row-per-lane, two matrices per wave (width-32 shuffles)
__device__ __forceinline__ void mm20(float* C, const float* A, const float* B) {
    float c[SA];
    #pragma unroll
    for (int j = 0; j < SA; ++j) c[j] = 0.0f;
    #pragma unroll
    for (int t = 0; t < SA; ++t) {
        float a = A[t];
        #pragma unroll
        for (int j = 0; j < SA; ++j)
            c[j] = fmaf(a, __shfl(B[j], t, 32), c[j]);
    }
    #pragma unroll
    for (int j = 0; j < SA; ++j) C[j] = c[j];
}

// ---------------- Kernel 2: fused expm + gather ----------------------------
__global__ __launch_bounds__(256) void expm_gather_kernel(
    const int* __restrict__ seqg,
    const int* __restrict__ rateIdx,
    const float* __restrict__ tauk,
    const float* __restrict__ Qg,
    float* __restrict__ out)
{
    __shared__ float sP[KDIM * SA * SA];   // 800 floats: P for both k
    __shared__ int   sSeq[LDIM];
    const int tid = threadIdx.x;
    const int mb  = blockIdx.x;            // mm*BDIM + bb
    const int mm  = mb >> 9;               // BDIM = 512
    const int wid = tid >> 6;

    if (wid == 1) {
        const int* sq = seqg + (size_t)mb * LDIM;
        for (int l = tid - 64; l < LDIM; l += 64) sSeq[l] = sq[l];
    }
    if (wid == 0) {
        const int lane = tid;
        const int half = lane >> 5;        // which k
        const int row  = lane & 31;
        const bool act = row < SA;

        float tau = softplusf(tauk[mm * NRATES + rateIdx[mb]]);

        float A[SA];
        const float* qb = Qg + (((mm * KDIM + half) * SA + (act ? row : 0)) * SA);
        #pragma unroll
        for (int j = 0; j < SA; ++j) A[j] = act ? tau * qb[j] : 0.0f;

        // inf-norm -> scaling count s
        float rn = 0.0f;
        #pragma unroll
        for (int j = 0; j < SA; ++j) rn += fabsf(A[j]);
        #pragma unroll
        for (int off = 16; off; off >>= 1) rn = fmaxf(rn, __shfl_xor(rn, off, 32));
        const float theta = 0.5f;
        int s = 0;
        if (rn > theta) s = (int)ceilf(log2f(rn / theta));
        if (s < 0) s = 0;
        if (s > 30) s = 30;
        float scale = exp2f((float)(-s));
        #pragma unroll
        for (int j = 0; j < SA; ++j) A[j] *= scale;
        int smax = max(s, __shfl_xor(s, 32, 64));

        // Paterson-Stockmeyer degree-8 Taylor of exp(A)
        float A2[SA], A3[SA], A4[SA], B1[SA], T[SA];
        mm20(A2, A, A);
        mm20(A3, A2, A);
        mm20(A4, A2, A2);
        #pragma unroll
        for (int j = 0; j < SA; ++j) {
            float id = (j == row) ? 1.0f : 0.0f;
            B1[j] = (1.0f/24.0f)*id + (1.0f/120.0f)*A[j] + (1.0f/720.0f)*A2[j]
                  + (1.0f/5040.0f)*A3[j] + (1.0f/40320.0f)*A4[j];
        }
        mm20(T, A4, B1);
        #pragma unroll
        for (int j = 0; j < SA; ++j) {
            float id = (j == row) ? 1.0f : 0.0f;
            T[j] += id + A[j] + 0.5f*A2[j] + (1.0f/6.0f)*A3[j];
        }
        // squaring
        for (int it = 0; it < smax; ++it) {
            float Tn[SA];
            mm20(Tn, T, T);
            bool doit = it < s;
            #pragma unroll
            for (int j = 0; j < SA; ++j) T[j] = doit ? Tn[j] : T[j];
        }
        if (act) {
            #pragma unroll
            for (int j = 0; j < SA; ++j)
                sP[(half * SA + row) * SA + j] = T[j];
        }
    }
    __syncthreads();

    // gather: out[mb, l, kk, s] = P[kk][seq[l]][s], as float4 chunks
    const float4* pv = reinterpret_cast<const float4*>(sP);
    float4* o4 = reinterpret_cast<float4*>(out) + (size_t)mb * (LDIM * KDIM * SA / 4);
    const int NCH = LDIM * KDIM * SA / 4;   // 5120
    for (int f = tid; f < NCH; f += 256) {
        int l  = f / 10;
        int ch = f - l * 10;
        int kk = (ch >= 5) ? 1 : 0;
        int c4 = ch - kk * 5;
        int sq = sSeq[l];
        o4[f] = pv[(kk * SA + sq) * 5 + c4];
    }
}

extern "C" void kernel_launch(void* const* d_in, const int* in_sizes, int n_in,
                              void* d_out, int out_size, void* d_ws, size_t ws_size,
                              hipStream_t stream) {
    const int*   seq  = (const int*)d_in[0];
    const int*   ridx = (const int*)d_in[1];
    const float* tauk = (const float*)d_in[2];
    const float* Ek   = (const float*)d_in[3];
    const float* eqk  = (const float*)d_in[4];
    float* out = (float*)d_out;
    float* Q   = (float*)d_ws;   // MDIM*KDIM*20*20 floats = 6.4 KB

    qmat_kernel<<<MDIM * KDIM, 64, 0, stream>>>(Ek, eqk, Q);
    expm_gather_kernel<<<MDIM * BDIM, 256, 0, stream>>>(seq, ridx, tauk, Q, out);
}

// Round 2
// 109.803 us; speedup vs baseline: 1.2653x; 1.2653x over previous
//
#include <hip/hip_runtime.h>
#include <math.h>

#define SA 20        // alphabet
#define KDIM 2
#define MDIM 2
#define BDIM 512
#define LDIM 512
#define NRATES 512
#define PPB 4        // (m,b) pairs per block (one per wave)
#define THREADS 256
#define NCH (LDIM * KDIM * SA / 4)   // 5120 float4 chunks per pair

__device__ __forceinline__ float softplusf(float x) {
    return fmaxf(x, 0.0f) + log1pf(expf(-fabsf(x)));
}

// C(row-per-lane regs) = A(row-per-lane regs) * B (LDS, 20x20 row-major, 16B-aligned)
// Same-address float4 LDS reads broadcast: conflict-free.
__device__ __forceinline__ void mmB(float* C, const float* A, const float* Bl) {
    #pragma unroll
    for (int j = 0; j < SA; ++j) C[j] = 0.0f;
    #pragma unroll
    for (int t = 0; t < SA; ++t) {
        const float a = A[t];
        const float4* row = reinterpret_cast<const float4*>(Bl + t * SA);
        #pragma unroll
        for (int q = 0; q < 5; ++q) {
            float4 b = row[q];
            C[4*q+0] = fmaf(a, b.x, C[4*q+0]);
            C[4*q+1] = fmaf(a, b.y, C[4*q+1]);
            C[4*q+2] = fmaf(a, b.z, C[4*q+2]);
            C[4*q+3] = fmaf(a, b.w, C[4*q+3]);
        }
    }
}

__device__ __forceinline__ void stageRow(float* dst, const float* T, int row, bool act) {
    if (act) {
        float4* d4 = reinterpret_cast<float4*>(dst + row * SA);
        #pragma unroll
        for (int q = 0; q < 5; ++q)
            d4[q] = make_float4(T[4*q+0], T[4*q+1], T[4*q+2], T[4*q+3]);
    }
}

__global__ __launch_bounds__(THREADS) void ancprobs_fused_kernel(
    const int*   __restrict__ seqg,
    const int*   __restrict__ rateIdx,
    const float* __restrict__ tauk,
    const float* __restrict__ Ek,
    const float* __restrict__ eqk,
    float*       __restrict__ out)
{
    __shared__ float sP[PPB * KDIM * SA * SA];   // 3200 floats = 12.8 KB (staging + final P)
    __shared__ int   sSeq[PPB * LDIM];           // 8 KB

    const int tid  = threadIdx.x;
    const int w    = tid >> 6;          // wave id == local pair id
    const int lane = tid & 63;
    const int mb   = blockIdx.x * PPB + w;   // global pair in [0, 1024)
    const int mm   = mb >> 9;                // BDIM = 512

    // ---- stage this pair's sequence (512 ints = 2 int4 per lane) ----
    {
        const int4* sq = reinterpret_cast<const int4*>(seqg + (size_t)mb * LDIM);
        int4* dst = reinterpret_cast<int4*>(sSeq + w * LDIM);
        dst[lane]      = sq[lane];
        dst[lane + 64] = sq[lane + 64];
    }

    const int  half = lane >> 5;        // which k
    const int  row  = lane & 31;
    const bool act  = row < SA;
    const int  mk   = mm * KDIM + half;
    float* stage = sP + (w * KDIM + half) * SA * SA;  // this half's 400-float slot

    // ---- fused qmat: p = softmax(eqk), R = softplus(sym(Ek)) off-diag, normalize ----
    float e = act ? eqk[mk * SA + row] : -INFINITY;
    float mx = e;
    #pragma unroll
    for (int off = 16; off; off >>= 1) mx = fmaxf(mx, __shfl_xor(mx, off, 32));
    float ex = act ? expf(e - mx) : 0.0f;
    float sm = ex;
    #pragma unroll
    for (int off = 16; off; off >>= 1) sm += __shfl_xor(sm, off, 32);
    float p_i = ex / sm;

    const int r0 = act ? row : 0;
    float A[SA];
    float dg = 0.0f;
    #pragma unroll
    for (int j = 0; j < SA; ++j) {
        float pj = __shfl(p_i, j, 32);
        float e1 = Ek[(mk * SA + r0) * SA + j];
        float e2 = Ek[(mk * SA + j) * SA + r0];
        float r  = (j == row) ? 0.0f : softplusf(0.5f * (e1 + e2));
        float q  = r * pj;
        A[j] = q;
        dg  += q;
    }
    float t_ = act ? p_i * dg : 0.0f;
    #pragma unroll
    for (int off = 16; off; off >>= 1) t_ += __shfl_xor(t_, off, 32);
    const float inv = 1.0f / fmaxf(t_, 1e-16f);

    const float tau = softplusf(tauk[mm * NRATES + rateIdx[mb]]);
    const float sc  = tau * inv;
    #pragma unroll
    for (int j = 0; j < SA; ++j)
        A[j] = act ? ((j == row) ? -dg * sc : A[j] * sc) : 0.0f;

    // ---- scaling: s = ceil(log2(||A||inf / theta)), theta = 1.0 ----
    float rn = 0.0f;
    #pragma unroll
    for (int j = 0; j < SA; ++j) rn += fabsf(A[j]);
    #pragma unroll
    for (int off = 16; off; off >>= 1) rn = fmaxf(rn, __shfl_xor(rn, off, 32));
    int s = 0;
    if (rn > 1.0f) s = (int)ceilf(log2f(rn));
    if (s < 0) s = 0;
    if (s > 30) s = 30;
    const float scale = exp2f((float)(-s));
    #pragma unroll
    for (int j = 0; j < SA; ++j) A[j] *= scale;
    const int smax = max(s, __shfl_xor(s, 32, 64));

    // ---- degree-6 Paterson-Stockmeyer Taylor: 3 matmuls ----
    float A2[SA], A3[SA], T[SA];
    stageRow(stage, A, row, act);
    mmB(A2, A, stage);
    mmB(A3, A2, stage);
    #pragma unroll
    for (int j = 0; j < SA; ++j) {
        float id = (j == row) ? 1.0f : 0.0f;
        T[j] = (1.0f/6.0f)*id + (1.0f/24.0f)*A[j] + (1.0f/120.0f)*A2[j] + (1.0f/720.0f)*A3[j];
    }
    stageRow(stage, T, row, act);      // stage B1
    {
        float P1[SA];
        mmB(P1, A3, stage);
        #pragma unroll
        for (int j = 0; j < SA; ++j) {
            float id = (j == row) ? 1.0f : 0.0f;
            T[j] = P1[j] + id + A[j] + 0.5f * A2[j];
        }
    }
    // ---- squarings (typically 0) ----
    for (int it = 0; it < smax; ++it) {
        stageRow(stage, T, row, act);
        float Tn[SA];
        mmB(Tn, T, stage);
        const bool doit = it < s;
        #pragma unroll
        for (int j = 0; j < SA; ++j) T[j] = doit ? Tn[j] : T[j];
    }
    stageRow(stage, T, row, act);      // final P into its slot

    __syncthreads();

    // ---- gather + stream out: out[mb,l,kk,:] = P[kk][seq[l]][:] as float4 ----
    const float4* pv = reinterpret_cast<const float4*>(sP);
    #pragma unroll 1
    for (int pr = 0; pr < PPB; ++pr) {
        float4* o4 = reinterpret_cast<float4*>(out) + (size_t)(blockIdx.x * PPB + pr) * NCH;
        const int* sq = sSeq + pr * LDIM;
        for (int f = tid; f < NCH; f += THREADS) {
            int l  = f / 10;
            int ch = f - l * 10;
            int kk = (ch >= 5) ? 1 : 0;
            int c4 = ch - kk * 5;
            o4[f] = pv[((pr * KDIM + kk) * SA + sq[l]) * 5 + c4];
        }
    }
}

extern "C" void kernel_launch(void* const* d_in, const int* in_sizes, int n_in,
                              void* d_out, int out_size, void* d_ws, size_t ws_size,
                              hipStream_t stream) {
    const int*   seq  = (const int*)d_in[0];
    const int*   ridx = (const int*)d_in[1];
    const float* tauk = (const float*)d_in[2];
    const float* Ek   = (const float*)d_in[3];
    const float* eqk  = (const float*)d_in[4];
    float* out = (float*)d_out;

    ancprobs_fused_kernel<<<(MDIM * BDIM) / PPB, THREADS, 0, stream>>>(
        seq, ridx, tauk, Ek, eqk, out);
}